// Round 4
// baseline (1741.879 us; speedup 1.0000x reference)
//
#include <hip/hip_runtime.h>
#include <hip/hip_bf16.h>
#include <math.h>

#define N_NODES 100000
#define N_EDGES 3200000
#define IN_F 256
#define OUT_F 64
#define LRELU_SLOPE 0.2f

#define NB 1563                         // buckets of 64 src nodes
#define NREP 32                         // replica counters (keyed blockIdx&31)
#define NC (NB * NREP)                  // 50016
#define SCAN_T 1024
#define SCAN_PER ((NC + SCAN_T - 1) / SCAN_T)   // 49
#define XPITCH 264                      // LDS row pitch in bf16 (2-way banks)
#define APITCH 65                       // acc row pitch in floats

typedef __attribute__((ext_vector_type(8))) short bf16x8;
typedef __attribute__((ext_vector_type(4))) float f32x4;

// ---------------------------------------------------------------------------
// K0: W (256x64 fp32) -> wt (64x256 bf16, transposed). 64 blocks x 256 thr.
// ---------------------------------------------------------------------------
__global__ __launch_bounds__(256) void wt_kernel(
    const float* __restrict__ W, __hip_bfloat16* __restrict__ wt) {
  wt[blockIdx.x * 256 + threadIdx.x] =
      __float2bfloat16(W[threadIdx.x * 64 + blockIdx.x]);
}

// ---------------------------------------------------------------------------
// K1: h = X @ W via bf16 MFMA 16x16x32, fused s_src = h@a[:64],
// s_dst = h@a[64:]. 64 rows/block, 4 waves; wave w owns rows [16w,16w+16).
// ---------------------------------------------------------------------------
__global__ __launch_bounds__(256) void gemm_h_kernel(
    const float* __restrict__ in, const __hip_bfloat16* __restrict__ wt,
    const float* __restrict__ a, __hip_bfloat16* __restrict__ h,
    float* __restrict__ s_src, float* __restrict__ s_dst) {
  __shared__ __hip_bfloat16 xl[64 * XPITCH];    // 33792 B
  const int tid = threadIdx.x;
  const int r0 = blockIdx.x * 64;

#pragma unroll
  for (int i = 0; i < 16; ++i) {
    const int e = i * 256 + tid;        // e in [0,4096)
    const int row = e >> 6, kc = e & 63;
    const int grow = r0 + row;
    float4 v = make_float4(0.f, 0.f, 0.f, 0.f);
    if (grow < N_NODES)
      v = *(const float4*)&in[(size_t)grow * IN_F + kc * 4];
    __hip_bfloat16 b4[4] = {__float2bfloat16(v.x), __float2bfloat16(v.y),
                            __float2bfloat16(v.z), __float2bfloat16(v.w)};
    *(uint2*)&xl[row * XPITCH + kc * 4] = *(uint2*)b4;
  }
  __syncthreads();

  const int w = tid >> 6, lane = tid & 63;
  const int lm = lane & 15, lg = lane >> 4;

  f32x4 acc[4];
#pragma unroll
  for (int ct = 0; ct < 4; ++ct) acc[ct] = (f32x4){0.f, 0.f, 0.f, 0.f};

  const __hip_bfloat16* xbase = &xl[(w * 16 + lm) * XPITCH + lg * 8];
  const __hip_bfloat16* wbase = &wt[(size_t)lm * IN_F + lg * 8];

#pragma unroll
  for (int kt = 0; kt < 8; ++kt) {
    bf16x8 af = *(const bf16x8*)(xbase + kt * 32);
#pragma unroll
    for (int ct = 0; ct < 4; ++ct) {
      bf16x8 bfr = *(const bf16x8*)(wbase + (size_t)ct * 16 * IN_F + kt * 32);
      acc[ct] = __builtin_amdgcn_mfma_f32_16x16x32_bf16(af, bfr, acc[ct],
                                                        0, 0, 0);
    }
  }

  float as[4], ad[4];
#pragma unroll
  for (int ct = 0; ct < 4; ++ct) {
    as[ct] = a[ct * 16 + lm];
    ad[ct] = a[OUT_F + ct * 16 + lm];
  }
#pragma unroll
  for (int reg = 0; reg < 4; ++reg) {
    const int row = r0 + w * 16 + lg * 4 + reg;
    float vs = 0.f, vd = 0.f;
    if (row < N_NODES) {
#pragma unroll
      for (int ct = 0; ct < 4; ++ct) {
        const float v = acc[ct][reg];
        h[(size_t)row * OUT_F + ct * 16 + lm] = __float2bfloat16(v);
        vs += v * as[ct];
        vd += v * ad[ct];
      }
    }
#pragma unroll
    for (int m = 1; m < 16; m <<= 1) {
      vs += __shfl_xor(vs, m);
      vd += __shfl_xor(vd, m);
    }
    if (lm == 0 && row < N_NODES) {
      s_src[row] = vs;
      s_dst[row] = vd;
    }
  }
}

// ---------------------------------------------------------------------------
// K2: bucket histogram, int4 reads (4 edges/thread), 32 replicas
// replica-major: slot = (blockIdx&31)*NB + bucket. Grid must match K4.
// ---------------------------------------------------------------------------
__global__ __launch_bounds__(256) void bucket_hist_kernel(
    const int4* __restrict__ src4, int* __restrict__ bctr) {
  const int t = blockIdx.x * 256 + threadIdx.x;
  const int4 s = src4[t];
  int* r = bctr + (blockIdx.x & 31) * NB;
  atomicAdd(&r[s.x >> 6], 1);
  atomicAdd(&r[s.y >> 6], 1);
  atomicAdd(&r[s.z >> 6], 1);
  atomicAdd(&r[s.w >> 6], 1);
}

// ---------------------------------------------------------------------------
// K3: single-block exclusive scan over ordinals o = bucket*32 + replica
// (slot (o&31)*NB + (o>>5)), in place -> scatter cursors + bstart[NB+1].
// ---------------------------------------------------------------------------
__global__ __launch_bounds__(SCAN_T) void bucket_scan_kernel(
    int* __restrict__ bctr, int* __restrict__ bstart) {
  __shared__ int ts[SCAN_T];
  const int t = threadIdx.x;
  int local[SCAN_PER];
  int sum = 0;
#pragma unroll
  for (int k = 0; k < SCAN_PER; ++k) {
    const int o = t * SCAN_PER + k;
    int v = 0;
    if (o < NC) v = bctr[(o & 31) * NB + (o >> 5)];
    local[k] = sum;
    sum += v;
  }
  ts[t] = sum;
  __syncthreads();
  for (int off = 1; off < SCAN_T; off <<= 1) {
    int tv = (t >= off) ? ts[t - off] : 0;
    __syncthreads();
    ts[t] += tv;
    __syncthreads();
  }
  const int texcl = (t > 0) ? ts[t - 1] : 0;
#pragma unroll
  for (int k = 0; k < SCAN_PER; ++k) {
    const int o = t * SCAN_PER + k;
    if (o < NC) {
      const int excl = texcl + local[k];
      bctr[(o & 31) * NB + (o >> 5)] = excl;
      if ((o & 31) == 0) bstart[o >> 5] = excl;
    }
  }
  if (t == 0) bstart[NB] = N_EDGES;
}

// ---------------------------------------------------------------------------
// K4: bucket-major partition, int4 reads, replica = blockIdx&31 (same
// mapping as K2). Replica sub-segments keep each XCD's write footprint
// ~1.6 MB -> L2-absorbed (no partial-line writeback thrash).
// ---------------------------------------------------------------------------
__global__ __launch_bounds__(256) void bucket_scatter_kernel(
    const int4* __restrict__ src4, const int4* __restrict__ dst4,
    int* __restrict__ bctr, unsigned int* __restrict__ staged) {
  const int t = blockIdx.x * 256 + threadIdx.x;
  const int4 s = src4[t];
  const int4 d = dst4[t];
  int* r = bctr + (blockIdx.x & 31) * NB;
  int p;
  p = atomicAdd(&r[s.x >> 6], 1);
  staged[p] = ((unsigned)(s.x & 63) << 17) | (unsigned)d.x;
  p = atomicAdd(&r[s.y >> 6], 1);
  staged[p] = ((unsigned)(s.y & 63) << 17) | (unsigned)d.y;
  p = atomicAdd(&r[s.z >> 6], 1);
  staged[p] = ((unsigned)(s.z & 63) << 17) | (unsigned)d.z;
  p = atomicAdd(&r[s.w >> 6], 1);
  staged[p] = ((unsigned)(s.w & 63) << 17) | (unsigned)d.w;
}

// ---------------------------------------------------------------------------
// K5: sort-free aggregation. One block per bucket; LDS accumulator tile
// acc[64 nodes][64 feats] (pitch 65) + rs[64]. Stream the bucket's edges
// in staged order (sequential reads). Lane-split: lane L handles edge
// (L>>4) of a 4-edge group, features (L&15)*4..+3 -> ushort4 h-gathers
// (8 B/lane). Accumulate via LDS atomicAdd (ds_add_f32). 2 barriers total.
// ---------------------------------------------------------------------------
__global__ __launch_bounds__(256) void aggregate_kernel(
    const int* __restrict__ bstart, const unsigned int* __restrict__ staged,
    const float* __restrict__ s_src, const float* __restrict__ s_dst,
    const __hip_bfloat16* __restrict__ h, float* __restrict__ out) {
  __shared__ float acc[64 * APITCH];    // 16640 B
  __shared__ float rs[64];
  __shared__ float ssrc[64];

  const int b = blockIdx.x;
  const int tid = threadIdx.x;
  const int lane = tid & 63;
  const int wv = tid >> 6;
  const int node0 = b << 6;

  // init: zero acc + rs, stage s_src
  for (int i = tid; i < 64 * APITCH; i += 256) acc[i] = 0.f;
  if (tid < 64) {
    rs[tid] = 0.f;
    ssrc[tid] = (node0 + tid < N_NODES) ? s_src[node0 + tid] : 0.f;
  }
  __syncthreads();

  const int e0 = bstart[b];
  const int e1 = bstart[b + 1];
  const int n = e1 - e0;
  const int q = (n + 3) >> 2;                 // per-wave chunk
  const int ws = min(e0 + wv * q, e1);
  const int we = min(ws + q, e1);

  const int g = lane >> 4;                    // edge slot within group of 4
  const int f0 = (lane & 15) * 4;             // this lane's feature base

  int i = ws;
  // main: 8 edges per iteration (2 groups of 4)
  for (; i + 8 <= we; i += 8) {
    const unsigned pk0 = staged[i + g];
    const unsigned pk1 = staged[i + 4 + g];
    const int ls0 = (int)(pk0 >> 17), d0 = (int)(pk0 & 0x1FFFFu);
    const int ls1 = (int)(pk1 >> 17), d1 = (int)(pk1 & 0x1FFFFu);
    const float sd0 = s_dst[d0];
    const float sd1 = s_dst[d1];
    const ushort4 hv0 = *(const ushort4*)&h[(size_t)d0 * OUT_F + f0];
    const ushort4 hv1 = *(const ushort4*)&h[(size_t)d1 * OUT_F + f0];
    const float sc0 = ssrc[ls0] + sd0;
    const float sc1 = ssrc[ls1] + sd1;
    const float ev0 = __expf(-fmaxf(sc0, LRELU_SLOPE * sc0));
    const float ev1 = __expf(-fmaxf(sc1, LRELU_SLOPE * sc1));
    float* a0 = &acc[ls0 * APITCH + f0];
    float* a1 = &acc[ls1 * APITCH + f0];
    atomicAdd(&a0[0], ev0 * __uint_as_float((unsigned)hv0.x << 16));
    atomicAdd(&a0[1], ev0 * __uint_as_float((unsigned)hv0.y << 16));
    atomicAdd(&a0[2], ev0 * __uint_as_float((unsigned)hv0.z << 16));
    atomicAdd(&a0[3], ev0 * __uint_as_float((unsigned)hv0.w << 16));
    atomicAdd(&a1[0], ev1 * __uint_as_float((unsigned)hv1.x << 16));
    atomicAdd(&a1[1], ev1 * __uint_as_float((unsigned)hv1.y << 16));
    atomicAdd(&a1[2], ev1 * __uint_as_float((unsigned)hv1.z << 16));
    atomicAdd(&a1[3], ev1 * __uint_as_float((unsigned)hv1.w << 16));
    if ((lane & 15) == 0) {
      atomicAdd(&rs[ls0], ev0);
      atomicAdd(&rs[ls1], ev1);
    }
  }
  // tail: up to 7 edges, masked per lane
  for (; i < we; i += 4) {
    const int e = i + g;
    const bool ok = e < we;
    const unsigned pk = staged[ok ? e : i];
    const int ls = (int)(pk >> 17), d = (int)(pk & 0x1FFFFu);
    const float sd = s_dst[d];
    const ushort4 hv = *(const ushort4*)&h[(size_t)d * OUT_F + f0];
    const float sc = ssrc[ls] + sd;
    const float ev = __expf(-fmaxf(sc, LRELU_SLOPE * sc));
    if (ok) {
      float* a0 = &acc[ls * APITCH + f0];
      atomicAdd(&a0[0], ev * __uint_as_float((unsigned)hv.x << 16));
      atomicAdd(&a0[1], ev * __uint_as_float((unsigned)hv.y << 16));
      atomicAdd(&a0[2], ev * __uint_as_float((unsigned)hv.z << 16));
      atomicAdd(&a0[3], ev * __uint_as_float((unsigned)hv.w << 16));
      if ((lane & 15) == 0) atomicAdd(&rs[ls], ev);
    }
  }
  __syncthreads();

  // epilogue: out = elu(acc / rowsum), coalesced
  for (int idx = tid; idx < 64 * 64; idx += 256) {
    const int ln = idx >> 6, f = idx & 63;
    const int node = node0 + ln;
    if (node < N_NODES) {
      const float v = acc[ln * APITCH + f] / rs[ln];
      out[(size_t)node * OUT_F + f] = v > 0.f ? v : expm1f(v);
    }
  }
}

extern "C" void kernel_launch(void* const* d_in, const int* in_sizes, int n_in,
                              void* d_out, int out_size, void* d_ws, size_t ws_size,
                              hipStream_t stream) {
  const float* in = (const float*)d_in[0];
  const int* edge = (const int*)d_in[1];
  const float* W = (const float*)d_in[2];
  const float* a = (const float*)d_in[3];
  float* out = (float*)d_out;

  const int4* src4 = (const int4*)edge;
  const int4* dst4 = (const int4*)(edge + N_EDGES);

  // workspace: identical to proven round-0 layout (26,639,100 B)
  char* p = (char*)d_ws;
  __hip_bfloat16* h = (__hip_bfloat16*)p;  p += (size_t)N_NODES * OUT_F * 2;
  float* s_src = (float*)p;                p += (size_t)N_NODES * 4;
  float* s_dst = (float*)p;                p += (size_t)N_NODES * 4;
  unsigned int* staged = (unsigned int*)p; p += (size_t)N_EDGES * 4;
  int* bctr = (int*)p;                     p += (size_t)NC * 4;
  int* bstart = (int*)p;                   p += (size_t)(NB + 1) * 4 + 12;
  __hip_bfloat16* wt = (__hip_bfloat16*)p; p += (size_t)OUT_F * IN_F * 2;

  hipMemsetAsync(bctr, 0, (size_t)NC * 4, stream);

  wt_kernel<<<OUT_F, 256, 0, stream>>>(W, wt);
  gemm_h_kernel<<<(N_NODES + 63) / 64, 256, 0, stream>>>(in, wt, a, h, s_src,
                                                         s_dst);
  bucket_hist_kernel<<<N_EDGES / 1024, 256, 0, stream>>>(src4, bctr);
  bucket_scan_kernel<<<1, SCAN_T, 0, stream>>>(bctr, bstart);
  bucket_scatter_kernel<<<N_EDGES / 1024, 256, 0, stream>>>(src4, dst4, bctr,
                                                            staged);
  aggregate_kernel<<<NB, 256, 0, stream>>>(bstart, staged, s_src, s_dst, h,
                                           out);
}

// Round 5
// 704.346 us; speedup vs baseline: 2.4730x; 2.4730x over previous
//
#include <hip/hip_runtime.h>
#include <hip/hip_bf16.h>
#include <math.h>

#define N_NODES 100000
#define N_EDGES 3200000
#define IN_F 256
#define OUT_F 64
#define LRELU_SLOPE 0.2f

#define NB 1563                         // buckets of 64 src nodes
#define NREP 32                         // replica counters (keyed blockIdx&31)
#define NC (NB * NREP)                  // 50016
#define SCAN_T 1024
#define SCAN_PER ((NC + SCAN_T - 1) / SCAN_T)   // 49
#define CAP 2560                        // per-chunk LDS edge capacity (max
                                        // bucket ~2250 for this graph -> 1 chunk)

typedef __attribute__((ext_vector_type(8))) short bf16x8;
typedef __attribute__((ext_vector_type(4))) float f32x4;

// ---------------------------------------------------------------------------
// K0: W (256x64 fp32) -> wt (64x256 bf16, transposed). 64 blocks x 256 thr.
// ---------------------------------------------------------------------------
__global__ __launch_bounds__(256) void wt_kernel(
    const float* __restrict__ W, __hip_bfloat16* __restrict__ wt) {
  wt[blockIdx.x * 256 + threadIdx.x] =
      __float2bfloat16(W[threadIdx.x * 64 + blockIdx.x]);
}

// ---------------------------------------------------------------------------
// K1: h = X @ W via bf16 MFMA 16x16x32, fused s_src = h@a[:64],
// s_dst = h@a[64:]. No LDS: X rows have zero cross-wave reuse, so A-frags
// load straight from global (lanes (lm,lg=0..3) cover 64B-aligned line
// quarters of row lm -> fully coalesced), converted fp32->bf16 in-register.
// A: m=lane&15, k=lg*8+kt*32+j; C/D: col=lane&15, row=lg*4+reg (m89).
// ---------------------------------------------------------------------------
__global__ __launch_bounds__(256) void gemm_h_kernel(
    const float* __restrict__ in, const __hip_bfloat16* __restrict__ wt,
    const float* __restrict__ a, __hip_bfloat16* __restrict__ h,
    float* __restrict__ s_src, float* __restrict__ s_dst) {
  const int tid = threadIdx.x;
  const int w = tid >> 6, lane = tid & 63;
  const int lm = lane & 15, lg = lane >> 4;
  const int arow = blockIdx.x * 64 + w * 16 + lm;   // this lane's A row
  const bool rv = arow < N_NODES;
  const float* xrow = &in[(size_t)(rv ? arow : 0) * IN_F + lg * 8];

  f32x4 acc[4];
#pragma unroll
  for (int ct = 0; ct < 4; ++ct) acc[ct] = (f32x4){0.f, 0.f, 0.f, 0.f};

  const __hip_bfloat16* wbase = &wt[(size_t)lm * IN_F + lg * 8];

#pragma unroll
  for (int kt = 0; kt < 8; ++kt) {
    float4 xa = make_float4(0.f, 0.f, 0.f, 0.f);
    float4 xb = make_float4(0.f, 0.f, 0.f, 0.f);
    if (rv) {
      xa = *(const float4*)(xrow + kt * 32);
      xb = *(const float4*)(xrow + kt * 32 + 4);
    }
    union { __hip_bfloat16 s[8]; bf16x8 v; } u;
    u.s[0] = __float2bfloat16(xa.x); u.s[1] = __float2bfloat16(xa.y);
    u.s[2] = __float2bfloat16(xa.z); u.s[3] = __float2bfloat16(xa.w);
    u.s[4] = __float2bfloat16(xb.x); u.s[5] = __float2bfloat16(xb.y);
    u.s[6] = __float2bfloat16(xb.z); u.s[7] = __float2bfloat16(xb.w);
    const bf16x8 af = u.v;
#pragma unroll
    for (int ct = 0; ct < 4; ++ct) {
      bf16x8 bfr = *(const bf16x8*)(wbase + (size_t)ct * 16 * IN_F + kt * 32);
      acc[ct] = __builtin_amdgcn_mfma_f32_16x16x32_bf16(af, bfr, acc[ct],
                                                        0, 0, 0);
    }
  }

  // epilogue: h store (bf16) + per-row s reductions over the 16-lane quad grp
  float as[4], ad[4];
#pragma unroll
  for (int ct = 0; ct < 4; ++ct) {
    as[ct] = a[ct * 16 + lm];
    ad[ct] = a[OUT_F + ct * 16 + lm];
  }
#pragma unroll
  for (int reg = 0; reg < 4; ++reg) {
    const int row = blockIdx.x * 64 + w * 16 + lg * 4 + reg;
    float vs = 0.f, vd = 0.f;
    if (row < N_NODES) {
#pragma unroll
      for (int ct = 0; ct < 4; ++ct) {
        const float v = acc[ct][reg];
        h[(size_t)row * OUT_F + ct * 16 + lm] = __float2bfloat16(v);
        vs += v * as[ct];
        vd += v * ad[ct];
      }
    }
#pragma unroll
    for (int m = 1; m < 16; m <<= 1) {    // reduce within quad group
      vs += __shfl_xor(vs, m);
      vd += __shfl_xor(vd, m);
    }
    if (lm == 0 && row < N_NODES) {
      s_src[row] = vs;
      s_dst[row] = vd;
    }
  }
}

// ---------------------------------------------------------------------------
// K2: bucket histogram, int4 reads (4 edges/thread), 32 replicas
// replica-major: slot = (blockIdx&31)*NB + bucket. Grid must match K4.
// ---------------------------------------------------------------------------
__global__ __launch_bounds__(256) void bucket_hist_kernel(
    const int4* __restrict__ src4, int* __restrict__ bctr) {
  const int t = blockIdx.x * 256 + threadIdx.x;
  const int4 s = src4[t];
  int* r = bctr + (blockIdx.x & 31) * NB;
  atomicAdd(&r[s.x >> 6], 1);
  atomicAdd(&r[s.y >> 6], 1);
  atomicAdd(&r[s.z >> 6], 1);
  atomicAdd(&r[s.w >> 6], 1);
}

// ---------------------------------------------------------------------------
// K3: single-block exclusive scan over ordinals o = bucket*32 + replica
// (slot (o&31)*NB + (o>>5)), in place -> scatter cursors + bstart[NB+1].
// ---------------------------------------------------------------------------
__global__ __launch_bounds__(SCAN_T) void bucket_scan_kernel(
    int* __restrict__ bctr, int* __restrict__ bstart) {
  __shared__ int ts[SCAN_T];
  const int t = threadIdx.x;
  int local[SCAN_PER];
  int sum = 0;
#pragma unroll
  for (int k = 0; k < SCAN_PER; ++k) {
    const int o = t * SCAN_PER + k;
    int v = 0;
    if (o < NC) v = bctr[(o & 31) * NB + (o >> 5)];
    local[k] = sum;
    sum += v;
  }
  ts[t] = sum;
  __syncthreads();
  for (int off = 1; off < SCAN_T; off <<= 1) {
    int tv = (t >= off) ? ts[t - off] : 0;
    __syncthreads();
    ts[t] += tv;
    __syncthreads();
  }
  const int texcl = (t > 0) ? ts[t - 1] : 0;
#pragma unroll
  for (int k = 0; k < SCAN_PER; ++k) {
    const int o = t * SCAN_PER + k;
    if (o < NC) {
      const int excl = texcl + local[k];
      bctr[(o & 31) * NB + (o >> 5)] = excl;
      if ((o & 31) == 0) bstart[o >> 5] = excl;
    }
  }
  if (t == 0) bstart[NB] = N_EDGES;
}

// ---------------------------------------------------------------------------
// K4: bucket-major partition, int4 reads, replica = blockIdx&31 (same
// mapping as K2). Replica-major staged layout keeps each XCD's write
// footprint ~1.6 MB -> L2-absorbed (no partial-line writeback thrash).
// ---------------------------------------------------------------------------
__global__ __launch_bounds__(256) void bucket_scatter_kernel(
    const int4* __restrict__ src4, const int4* __restrict__ dst4,
    int* __restrict__ bctr, unsigned int* __restrict__ staged) {
  const int t = blockIdx.x * 256 + threadIdx.x;
  const int4 s = src4[t];
  const int4 d = dst4[t];
  int* r = bctr + (blockIdx.x & 31) * NB;
  int p;
  p = atomicAdd(&r[s.x >> 6], 1);
  staged[p] = ((unsigned)(s.x & 63) << 17) | (unsigned)d.x;
  p = atomicAdd(&r[s.y >> 6], 1);
  staged[p] = ((unsigned)(s.y & 63) << 17) | (unsigned)d.y;
  p = atomicAdd(&r[s.z >> 6], 1);
  staged[p] = ((unsigned)(s.z & 63) << 17) | (unsigned)d.z;
  p = atomicAdd(&r[s.w >> 6], 1);
  staged[p] = ((unsigned)(s.w & 63) << 17) | (unsigned)d.w;
}

// ---------------------------------------------------------------------------
// K5: one block per bucket. LDS counting sort by local src (ee computed
// once per edge), then register accumulate: wave owns 16 nodes, 8-edge
// batched bf16 gathers (deeper MLP than the 4-batch baseline). CAP=2560
// -> 21.5 KB LDS -> 7 blocks/CU (vs 6 at CAP=3072); one chunk per bucket
// for this graph (chunk loop retained for generality).
// ---------------------------------------------------------------------------
__global__ __launch_bounds__(256) void sort_aggregate_kernel(
    const int* __restrict__ bstart, const unsigned int* __restrict__ staged,
    const float* __restrict__ s_src, const float* __restrict__ s_dst,
    const __hip_bfloat16* __restrict__ h, float* __restrict__ out) {
  __shared__ uint2 eds[CAP];            // 20480 B
  __shared__ float ssrc[64];
  __shared__ int lcnt[64];
  __shared__ int lstart[65];
  __shared__ int lcur[64];

  const int b = blockIdx.x;
  const int tid = threadIdx.x;
  const int lane = tid & 63;
  const int wv = tid >> 6;
  const int node0 = b << 6;

  if (tid < 64)
    ssrc[tid] = (node0 + tid < N_NODES) ? s_src[node0 + tid] : 0.f;

  const int e0 = bstart[b];
  const int e1 = bstart[b + 1];

  float acc[16], rsn[16];
#pragma unroll
  for (int j = 0; j < 16; ++j) { acc[j] = 0.f; rsn[j] = 0.f; }

  for (int c0 = e0; c0 < e1; c0 += CAP) {
    const int cc = min(CAP, e1 - c0);
    __syncthreads();
    if (tid < 64) lcnt[tid] = 0;
    __syncthreads();

    // phase A: histogram of local src
    for (int i = tid; i < cc; i += 256)
      atomicAdd(&lcnt[staged[c0 + i] >> 17], 1);
    __syncthreads();

    // wave-0 scan of the 64 counters
    if (tid < 64) {
      int v = lcnt[tid];
#pragma unroll
      for (int off = 1; off < 64; off <<= 1) {
        int tv = __shfl_up(v, off);
        if (lane >= off) v += tv;
      }
      lstart[tid + 1] = v;
      if (tid == 0) lstart[0] = 0;
      lcur[tid] = v - lcnt[tid];
    }
    __syncthreads();

    // phase B: ee once per edge, scatter sorted into LDS (packed b64)
    for (int i = tid; i < cc; i += 256) {
      const unsigned pk = staged[c0 + i];
      const int ls = (int)(pk >> 17);
      const int d = (int)(pk & 0x1FFFFu);
      const float sc = ssrc[ls] + s_dst[d];
      const float lr = sc > 0.f ? sc : LRELU_SLOPE * sc;
      const float ev = __expf(-lr);
      const int p = atomicAdd(&lcur[ls], 1);
      eds[p] = make_uint2((unsigned)d, __float_as_uint(ev));
    }
    __syncthreads();

    // phase C: wave wv accumulates its 16 nodes in registers, 8-edge batch
#pragma unroll
    for (int j = 0; j < 16; ++j) {
      const int n = wv + 4 * j;
      const int iend = lstart[n + 1];
      int i = lstart[n];
      float p0 = 0.f, p1 = 0.f, rv = 0.f;
      for (; i + 8 <= iend; i += 8) {
        uint2 q[8];
#pragma unroll
        for (int k = 0; k < 8; ++k) q[k] = eds[i + k];
        float hv[8];
#pragma unroll
        for (int k = 0; k < 8; ++k)
          hv[k] = __bfloat162float(h[(size_t)q[k].x * OUT_F + lane]);
        float vv[8];
#pragma unroll
        for (int k = 0; k < 8; ++k) vv[k] = __uint_as_float(q[k].y);
#pragma unroll
        for (int k = 0; k < 8; k += 2) {
          p0 += vv[k] * hv[k];
          p1 += vv[k + 1] * hv[k + 1];
          rv += vv[k] + vv[k + 1];
        }
      }
      for (; i < iend; ++i) {
        const uint2 q0 = eds[i];
        const float v0 = __uint_as_float(q0.y);
        p0 += v0 * __bfloat162float(h[(size_t)q0.x * OUT_F + lane]);
        rv += v0;
      }
      acc[j] += p0 + p1;
      rsn[j] += rv;
    }
  }

  // epilogue: out = elu(acc / rowsum)
#pragma unroll
  for (int j = 0; j < 16; ++j) {
    const int node = node0 + wv + 4 * j;
    if (node < N_NODES) {
      const float v = acc[j] / rsn[j];
      out[(size_t)node * OUT_F + lane] = v > 0.f ? v : expm1f(v);
    }
  }
}

extern "C" void kernel_launch(void* const* d_in, const int* in_sizes, int n_in,
                              void* d_out, int out_size, void* d_ws, size_t ws_size,
                              hipStream_t stream) {
  const float* in = (const float*)d_in[0];
  const int* edge = (const int*)d_in[1];
  const float* W = (const float*)d_in[2];
  const float* a = (const float*)d_in[3];
  float* out = (float*)d_out;

  const int4* src4 = (const int4*)edge;
  const int4* dst4 = (const int4*)(edge + N_EDGES);

  // workspace: identical to proven round-0 layout (26,639,100 B)
  char* p = (char*)d_ws;
  __hip_bfloat16* h = (__hip_bfloat16*)p;  p += (size_t)N_NODES * OUT_F * 2;
  float* s_src = (float*)p;                p += (size_t)N_NODES * 4;
  float* s_dst = (float*)p;                p += (size_t)N_NODES * 4;
  unsigned int* staged = (unsigned int*)p; p += (size_t)N_EDGES * 4;
  int* bctr = (int*)p;                     p += (size_t)NC * 4;
  int* bstart = (int*)p;                   p += (size_t)(NB + 1) * 4 + 12;
  __hip_bfloat16* wt = (__hip_bfloat16*)p; p += (size_t)OUT_F * IN_F * 2;

  hipMemsetAsync(bctr, 0, (size_t)NC * 4, stream);

  wt_kernel<<<OUT_F, 256, 0, stream>>>(W, wt);
  gemm_h_kernel<<<(N_NODES + 63) / 64, 256, 0, stream>>>(in, wt, a, h, s_src,
                                                         s_dst);
  bucket_hist_kernel<<<N_EDGES / 1024, 256, 0, stream>>>(src4, bctr);
  bucket_scan_kernel<<<1, SCAN_T, 0, stream>>>(bctr, bstart);
  bucket_scatter_kernel<<<N_EDGES / 1024, 256, 0, stream>>>(src4, dst4, bctr,
                                                            staged);
  sort_aggregate_kernel<<<NB, 256, 0, stream>>>(bstart, staged, s_src, s_dst,
                                                h, out);
}

// Round 6
// 563.311 us; speedup vs baseline: 3.0922x; 1.2504x over previous
//
#include <hip/hip_runtime.h>
#include <hip/hip_bf16.h>
#include <math.h>

#define N_NODES 100000
#define N_EDGES 3200000
#define IN_F 256
#define OUT_F 64
#define LRELU_SLOPE 0.2f

#define NB 1563                         // buckets of 64 src nodes
#define NREP 32                         // replica counters (keyed blockIdx&31)
#define NC (NB * NREP)                  // 50016
#define SCAN_NBLK ((NC + 255) / 256)    // 196 blocks for the parallel scan
#define CAP 3072                        // per-chunk LDS edge capacity

typedef __attribute__((ext_vector_type(8))) short bf16x8;
typedef __attribute__((ext_vector_type(4))) float f32x4;

// ---------------------------------------------------------------------------
// K0: W (256x64 fp32) -> wt (64x256 bf16, transposed). 64 blocks x 256 thr.
// ---------------------------------------------------------------------------
__global__ __launch_bounds__(256) void wt_kernel(
    const float* __restrict__ W, __hip_bfloat16* __restrict__ wt) {
  wt[blockIdx.x * 256 + threadIdx.x] =
      __float2bfloat16(W[threadIdx.x * 64 + blockIdx.x]);
}

// ---------------------------------------------------------------------------
// K1: h = X @ W via bf16 MFMA 16x16x32, fused s_src = h@a[:64],
// s_dst = h@a[64:]. No LDS: X rows have zero cross-wave reuse, so A-frags
// load straight from global (lanes (lm,lg=0..3) cover 64B-aligned line
// quarters of row lm -> fully coalesced), converted fp32->bf16 in-register.
// (round-5 version: measured ~13 us faster than LDS-staged variant)
// ---------------------------------------------------------------------------
__global__ __launch_bounds__(256) void gemm_h_kernel(
    const float* __restrict__ in, const __hip_bfloat16* __restrict__ wt,
    const float* __restrict__ a, __hip_bfloat16* __restrict__ h,
    float* __restrict__ s_src, float* __restrict__ s_dst) {
  const int tid = threadIdx.x;
  const int w = tid >> 6, lane = tid & 63;
  const int lm = lane & 15, lg = lane >> 4;
  const int arow = blockIdx.x * 64 + w * 16 + lm;   // this lane's A row
  const bool rv = arow < N_NODES;
  const float* xrow = &in[(size_t)(rv ? arow : 0) * IN_F + lg * 8];

  f32x4 acc[4];
#pragma unroll
  for (int ct = 0; ct < 4; ++ct) acc[ct] = (f32x4){0.f, 0.f, 0.f, 0.f};

  const __hip_bfloat16* wbase = &wt[(size_t)lm * IN_F + lg * 8];

#pragma unroll
  for (int kt = 0; kt < 8; ++kt) {
    float4 xa = make_float4(0.f, 0.f, 0.f, 0.f);
    float4 xb = make_float4(0.f, 0.f, 0.f, 0.f);
    if (rv) {
      xa = *(const float4*)(xrow + kt * 32);
      xb = *(const float4*)(xrow + kt * 32 + 4);
    }
    union { __hip_bfloat16 s[8]; bf16x8 v; } u;
    u.s[0] = __float2bfloat16(xa.x); u.s[1] = __float2bfloat16(xa.y);
    u.s[2] = __float2bfloat16(xa.z); u.s[3] = __float2bfloat16(xa.w);
    u.s[4] = __float2bfloat16(xb.x); u.s[5] = __float2bfloat16(xb.y);
    u.s[6] = __float2bfloat16(xb.z); u.s[7] = __float2bfloat16(xb.w);
    const bf16x8 af = u.v;
#pragma unroll
    for (int ct = 0; ct < 4; ++ct) {
      bf16x8 bfr = *(const bf16x8*)(wbase + (size_t)ct * 16 * IN_F + kt * 32);
      acc[ct] = __builtin_amdgcn_mfma_f32_16x16x32_bf16(af, bfr, acc[ct],
                                                        0, 0, 0);
    }
  }

  float as[4], ad[4];
#pragma unroll
  for (int ct = 0; ct < 4; ++ct) {
    as[ct] = a[ct * 16 + lm];
    ad[ct] = a[OUT_F + ct * 16 + lm];
  }
#pragma unroll
  for (int reg = 0; reg < 4; ++reg) {
    const int row = blockIdx.x * 64 + w * 16 + lg * 4 + reg;
    float vs = 0.f, vd = 0.f;
    if (row < N_NODES) {
#pragma unroll
      for (int ct = 0; ct < 4; ++ct) {
        const float v = acc[ct][reg];
        h[(size_t)row * OUT_F + ct * 16 + lm] = __float2bfloat16(v);
        vs += v * as[ct];
        vd += v * ad[ct];
      }
    }
#pragma unroll
    for (int m = 1; m < 16; m <<= 1) {    // reduce within quad group
      vs += __shfl_xor(vs, m);
      vd += __shfl_xor(vd, m);
    }
    if (lm == 0 && row < N_NODES) {
      s_src[row] = vs;
      s_dst[row] = vd;
    }
  }
}

// ---------------------------------------------------------------------------
// K2: bucket histogram, int4 reads (4 edges/thread), 32 replicas
// replica-major: slot = (blockIdx&31)*NB + bucket. Grid must match K4.
// ---------------------------------------------------------------------------
__global__ __launch_bounds__(256) void bucket_hist_kernel(
    const int4* __restrict__ src4, int* __restrict__ bctr) {
  const int t = blockIdx.x * 256 + threadIdx.x;
  const int4 s = src4[t];
  int* r = bctr + (blockIdx.x & 31) * NB;
  atomicAdd(&r[s.x >> 6], 1);
  atomicAdd(&r[s.y >> 6], 1);
  atomicAdd(&r[s.z >> 6], 1);
  atomicAdd(&r[s.w >> 6], 1);
}

// ---------------------------------------------------------------------------
// K3 (parallel, 3 launches): hierarchical exclusive scan over ordinals
// o = bucket*32 + replica (slot (o&31)*NB + (o>>5)). The old single-block
// scan serialized ~100K scattered L2 accesses on ONE CU; this uses 196
// blocks. pt[] aliases staged (written only later by scatter).
// ---------------------------------------------------------------------------
__global__ __launch_bounds__(256) void scan1_kernel(
    int* __restrict__ bctr, int* __restrict__ pt) {
  __shared__ int ws[4];
  const int tid = threadIdx.x, lane = tid & 63, wv = tid >> 6;
  const int o = blockIdx.x * 256 + tid;
  int v = 0;
  if (o < NC) v = bctr[(o & 31) * NB + (o >> 5)];
  int incl = v;
#pragma unroll
  for (int off = 1; off < 64; off <<= 1) {
    const int t = __shfl_up(incl, off);
    if (lane >= off) incl += t;
  }
  if (lane == 63) ws[wv] = incl;
  __syncthreads();
  int base = 0;
#pragma unroll
  for (int k = 0; k < 4; ++k)
    if (k < wv) base += ws[k];
  if (o < NC) bctr[(o & 31) * NB + (o >> 5)] = base + incl - v;  // excl-in-blk
  if (tid == 255) pt[blockIdx.x] = base + incl;                  // block total
}

__global__ __launch_bounds__(256) void scan2_kernel(int* __restrict__ pt) {
  __shared__ int ws[4];
  const int tid = threadIdx.x, lane = tid & 63, wv = tid >> 6;
  int v = (tid < SCAN_NBLK) ? pt[tid] : 0;
  int incl = v;
#pragma unroll
  for (int off = 1; off < 64; off <<= 1) {
    const int t = __shfl_up(incl, off);
    if (lane >= off) incl += t;
  }
  if (lane == 63) ws[wv] = incl;
  __syncthreads();
  int base = 0;
#pragma unroll
  for (int k = 0; k < 4; ++k)
    if (k < wv) base += ws[k];
  if (tid < SCAN_NBLK) pt[tid] = base + incl - v;                // exclusive
}

__global__ __launch_bounds__(256) void scan3_kernel(
    int* __restrict__ bctr, const int* __restrict__ pt,
    int* __restrict__ bstart) {
  const int o = blockIdx.x * 256 + threadIdx.x;
  if (o < NC) {
    const int slot = (o & 31) * NB + (o >> 5);
    const int excl = bctr[slot] + pt[blockIdx.x];
    bctr[slot] = excl;
    if ((o & 31) == 0) bstart[o >> 5] = excl;
  }
  if (o == 0) bstart[NB] = N_EDGES;
}

// ---------------------------------------------------------------------------
// K4: bucket-major partition, int4 reads, replica = blockIdx&31 (same
// mapping as K2). Replica-major staged layout keeps each XCD's write
// footprint ~1.6 MB -> L2-absorbed (no partial-line writeback thrash).
// ---------------------------------------------------------------------------
__global__ __launch_bounds__(256) void bucket_scatter_kernel(
    const int4* __restrict__ src4, const int4* __restrict__ dst4,
    int* __restrict__ bctr, unsigned int* __restrict__ staged) {
  const int t = blockIdx.x * 256 + threadIdx.x;
  const int4 s = src4[t];
  const int4 d = dst4[t];
  int* r = bctr + (blockIdx.x & 31) * NB;
  int p;
  p = atomicAdd(&r[s.x >> 6], 1);
  staged[p] = ((unsigned)(s.x & 63) << 17) | (unsigned)d.x;
  p = atomicAdd(&r[s.y >> 6], 1);
  staged[p] = ((unsigned)(s.y & 63) << 17) | (unsigned)d.y;
  p = atomicAdd(&r[s.z >> 6], 1);
  staged[p] = ((unsigned)(s.z & 63) << 17) | (unsigned)d.z;
  p = atomicAdd(&r[s.w >> 6], 1);
  staged[p] = ((unsigned)(s.w & 63) << 17) | (unsigned)d.w;
}

// ---------------------------------------------------------------------------
// K5: one block per bucket. LDS counting sort by local src (ee computed
// once per edge), then register accumulate: wave owns 16 nodes, 4-edge
// batched bf16 gathers. Byte-exact revert to the proven 152 us version
// (round-5's 8-edge batch + CAP 2560 regressed to 187 us).
// ---------------------------------------------------------------------------
__global__ __launch_bounds__(256) void sort_aggregate_kernel(
    const int* __restrict__ bstart, const unsigned int* __restrict__ staged,
    const float* __restrict__ s_src, const float* __restrict__ s_dst,
    const __hip_bfloat16* __restrict__ h, float* __restrict__ out) {
  __shared__ uint2 eds[CAP];            // 24 KB
  __shared__ float ssrc[64];
  __shared__ int lcnt[64];
  __shared__ int lstart[65];
  __shared__ int lcur[64];

  const int b = blockIdx.x;
  const int tid = threadIdx.x;
  const int lane = tid & 63;
  const int wv = tid >> 6;
  const int node0 = b << 6;

  if (tid < 64)
    ssrc[tid] = (node0 + tid < N_NODES) ? s_src[node0 + tid] : 0.f;

  const int e0 = bstart[b];
  const int e1 = bstart[b + 1];

  float acc[16], rsn[16];
#pragma unroll
  for (int j = 0; j < 16; ++j) { acc[j] = 0.f; rsn[j] = 0.f; }

  for (int c0 = e0; c0 < e1; c0 += CAP) {
    const int cc = min(CAP, e1 - c0);
    __syncthreads();
    if (tid < 64) lcnt[tid] = 0;
    __syncthreads();

    // phase A: histogram of local src
    for (int i = tid; i < cc; i += 256)
      atomicAdd(&lcnt[staged[c0 + i] >> 17], 1);
    __syncthreads();

    // wave-0 scan of the 64 counters
    if (tid < 64) {
      int v = lcnt[tid];
#pragma unroll
      for (int off = 1; off < 64; off <<= 1) {
        int tv = __shfl_up(v, off);
        if (lane >= off) v += tv;
      }
      lstart[tid + 1] = v;
      if (tid == 0) lstart[0] = 0;
      lcur[tid] = v - lcnt[tid];
    }
    __syncthreads();

    // phase B: ee once per edge, scatter sorted into LDS (packed b64)
    for (int i = tid; i < cc; i += 256) {
      const unsigned pk = staged[c0 + i];
      const int ls = (int)(pk >> 17);
      const int d = (int)(pk & 0x1FFFFu);
      const float sc = ssrc[ls] + s_dst[d];
      const float lr = sc > 0.f ? sc : LRELU_SLOPE * sc;
      const float ev = __expf(-lr);
      const int p = atomicAdd(&lcur[ls], 1);
      eds[p] = make_uint2((unsigned)d, __float_as_uint(ev));
    }
    __syncthreads();

    // phase C: wave wv accumulates its 16 nodes in registers
#pragma unroll
    for (int j = 0; j < 16; ++j) {
      const int n = wv + 4 * j;
      const int iend = lstart[n + 1];
      int i = lstart[n];
      float p0 = 0.f, p1 = 0.f, rv = 0.f;
      for (; i + 4 <= iend; i += 4) {
        const uint2 q0 = eds[i + 0], q1 = eds[i + 1];
        const uint2 q2 = eds[i + 2], q3 = eds[i + 3];
        const float v0 = __uint_as_float(q0.y), v1 = __uint_as_float(q1.y);
        const float v2 = __uint_as_float(q2.y), v3 = __uint_as_float(q3.y);
        const float h0 = __bfloat162float(h[(size_t)q0.x * OUT_F + lane]);
        const float h1 = __bfloat162float(h[(size_t)q1.x * OUT_F + lane]);
        const float h2 = __bfloat162float(h[(size_t)q2.x * OUT_F + lane]);
        const float h3 = __bfloat162float(h[(size_t)q3.x * OUT_F + lane]);
        p0 += v0 * h0 + v2 * h2;
        p1 += v1 * h1 + v3 * h3;
        rv += (v0 + v1) + (v2 + v3);
      }
      for (; i < iend; ++i) {
        const uint2 q0 = eds[i];
        const float v0 = __uint_as_float(q0.y);
        p0 += v0 * __bfloat162float(h[(size_t)q0.x * OUT_F + lane]);
        rv += v0;
      }
      acc[j] += p0 + p1;
      rsn[j] += rv;
    }
  }

  // epilogue: out = elu(acc / rowsum)
#pragma unroll
  for (int j = 0; j < 16; ++j) {
    const int node = node0 + wv + 4 * j;
    if (node < N_NODES) {
      const float v = acc[j] / rsn[j];
      out[(size_t)node * OUT_F + lane] = v > 0.f ? v : expm1f(v);
    }
  }
}

extern "C" void kernel_launch(void* const* d_in, const int* in_sizes, int n_in,
                              void* d_out, int out_size, void* d_ws, size_t ws_size,
                              hipStream_t stream) {
  const float* in = (const float*)d_in[0];
  const int* edge = (const int*)d_in[1];
  const float* W = (const float*)d_in[2];
  const float* a = (const float*)d_in[3];
  float* out = (float*)d_out;

  const int4* src4 = (const int4*)edge;
  const int4* dst4 = (const int4*)(edge + N_EDGES);

  // workspace: identical to proven round-0 layout (26,639,100 B)
  char* p = (char*)d_ws;
  __hip_bfloat16* h = (__hip_bfloat16*)p;  p += (size_t)N_NODES * OUT_F * 2;
  float* s_src = (float*)p;                p += (size_t)N_NODES * 4;
  float* s_dst = (float*)p;                p += (size_t)N_NODES * 4;
  unsigned int* staged = (unsigned int*)p; p += (size_t)N_EDGES * 4;
  int* bctr = (int*)p;                     p += (size_t)NC * 4;
  int* bstart = (int*)p;                   p += (size_t)(NB + 1) * 4 + 12;
  __hip_bfloat16* wt = (__hip_bfloat16*)p; p += (size_t)OUT_F * IN_F * 2;

  // scan partials alias staged: consumed by scan3 before scatter writes it
  int* pt = (int*)staged;

  hipMemsetAsync(bctr, 0, (size_t)NC * 4, stream);

  wt_kernel<<<OUT_F, 256, 0, stream>>>(W, wt);
  gemm_h_kernel<<<(N_NODES + 63) / 64, 256, 0, stream>>>(in, wt, a, h, s_src,
                                                         s_dst);
  bucket_hist_kernel<<<N_EDGES / 1024, 256, 0, stream>>>(src4, bctr);
  scan1_kernel<<<SCAN_NBLK, 256, 0, stream>>>(bctr, pt);
  scan2_kernel<<<1, 256, 0, stream>>>(pt);
  scan3_kernel<<<SCAN_NBLK, 256, 0, stream>>>(bctr, pt, bstart);
  bucket_scatter_kernel<<<N_EDGES / 1024, 256, 0, stream>>>(src4, dst4, bctr,
                                                            staged);
  sort_aggregate_kernel<<<NB, 256, 0, stream>>>(bstart, staged, s_src, s_dst,
                                                h, out);
}

// Round 7
// 416.504 us; speedup vs baseline: 4.1821x; 1.3525x over previous
//
#include <hip/hip_runtime.h>
#include <hip/hip_bf16.h>
#include <math.h>

#define N_NODES 100000
#define N_EDGES 3200000
#define IN_F 256
#define OUT_F 64
#define LRELU_SLOPE 0.2f

#define NB 1563                         // buckets of 64 src nodes
#define CAP 3072                        // K5 per-chunk LDS edge capacity

// deterministic partition geometry
#define NBLK2 784                       // partition blocks (8 XCD groups x 98)
#define EPB 4096                        // edges per partition block
#define XG 98                           // blocks per XCD group
#define NE (NBLK2 * NB)                 // 1,225,392 scan elements
#define NS1 ((NE + 255) / 256)          // 4787 scan1 blocks
#define S2PER ((NS1 + 255) / 256)       // 19 elems/thread in scan2

typedef __attribute__((ext_vector_type(8))) short bf16x8;
typedef __attribute__((ext_vector_type(4))) float f32x4;

// ---------------------------------------------------------------------------
// K0: W (256x64 fp32) -> wt (64x256 bf16, transposed). 64 blocks x 256 thr.
// ---------------------------------------------------------------------------
__global__ __launch_bounds__(256) void wt_kernel(
    const float* __restrict__ W, __hip_bfloat16* __restrict__ wt) {
  wt[blockIdx.x * 256 + threadIdx.x] =
      __float2bfloat16(W[threadIdx.x * 64 + blockIdx.x]);
}

// ---------------------------------------------------------------------------
// K1: h = X @ W via bf16 MFMA 16x16x32, fused s_src = h@a[:64],
// s_dst = h@a[64:]. No LDS (proven ~13 us faster than LDS-staged).
// ---------------------------------------------------------------------------
__global__ __launch_bounds__(256) void gemm_h_kernel(
    const float* __restrict__ in, const __hip_bfloat16* __restrict__ wt,
    const float* __restrict__ a, __hip_bfloat16* __restrict__ h,
    float* __restrict__ s_src, float* __restrict__ s_dst) {
  const int tid = threadIdx.x;
  const int w = tid >> 6, lane = tid & 63;
  const int lm = lane & 15, lg = lane >> 4;
  const int arow = blockIdx.x * 64 + w * 16 + lm;   // this lane's A row
  const bool rv = arow < N_NODES;
  const float* xrow = &in[(size_t)(rv ? arow : 0) * IN_F + lg * 8];

  f32x4 acc[4];
#pragma unroll
  for (int ct = 0; ct < 4; ++ct) acc[ct] = (f32x4){0.f, 0.f, 0.f, 0.f};

  const __hip_bfloat16* wbase = &wt[(size_t)lm * IN_F + lg * 8];

#pragma unroll
  for (int kt = 0; kt < 8; ++kt) {
    float4 xa = make_float4(0.f, 0.f, 0.f, 0.f);
    float4 xb = make_float4(0.f, 0.f, 0.f, 0.f);
    if (rv) {
      xa = *(const float4*)(xrow + kt * 32);
      xb = *(const float4*)(xrow + kt * 32 + 4);
    }
    union { __hip_bfloat16 s[8]; bf16x8 v; } u;
    u.s[0] = __float2bfloat16(xa.x); u.s[1] = __float2bfloat16(xa.y);
    u.s[2] = __float2bfloat16(xa.z); u.s[3] = __float2bfloat16(xa.w);
    u.s[4] = __float2bfloat16(xb.x); u.s[5] = __float2bfloat16(xb.y);
    u.s[6] = __float2bfloat16(xb.z); u.s[7] = __float2bfloat16(xb.w);
    const bf16x8 af = u.v;
#pragma unroll
    for (int ct = 0; ct < 4; ++ct) {
      bf16x8 bfr = *(const bf16x8*)(wbase + (size_t)ct * 16 * IN_F + kt * 32);
      acc[ct] = __builtin_amdgcn_mfma_f32_16x16x32_bf16(af, bfr, acc[ct],
                                                        0, 0, 0);
    }
  }

  float as[4], ad[4];
#pragma unroll
  for (int ct = 0; ct < 4; ++ct) {
    as[ct] = a[ct * 16 + lm];
    ad[ct] = a[OUT_F + ct * 16 + lm];
  }
#pragma unroll
  for (int reg = 0; reg < 4; ++reg) {
    const int row = blockIdx.x * 64 + w * 16 + lg * 4 + reg;
    float vs = 0.f, vd = 0.f;
    if (row < N_NODES) {
#pragma unroll
      for (int ct = 0; ct < 4; ++ct) {
        const float v = acc[ct][reg];
        h[(size_t)row * OUT_F + ct * 16 + lm] = __float2bfloat16(v);
        vs += v * as[ct];
        vd += v * ad[ct];
      }
    }
#pragma unroll
    for (int m = 1; m < 16; m <<= 1) {    // reduce within quad group
      vs += __shfl_xor(vs, m);
      vd += __shfl_xor(vd, m);
    }
    if (lm == 0 && row < N_NODES) {
      s_src[row] = vs;
      s_dst[row] = vd;
    }
  }
}

// ---------------------------------------------------------------------------
// K2: per-block LDS histogram over all NB buckets -> cnt2d[block][bucket].
// Zero global atomics. 784 blocks x 4096 edges; ~3.2M LDS atomics total.
// ---------------------------------------------------------------------------
__global__ __launch_bounds__(256) void hist2d_kernel(
    const int4* __restrict__ src4, int* __restrict__ cnt2d) {
  __shared__ int lh[NB];
  const int tid = threadIdx.x, b = blockIdx.x;
  for (int j = tid; j < NB; j += 256) lh[j] = 0;
  __syncthreads();
#pragma unroll
  for (int i = 0; i < 4; ++i) {
    const int idx4 = b * (EPB / 4) + i * 256 + tid;
    if (idx4 < N_EDGES / 4) {
      const int4 s = src4[idx4];
      atomicAdd(&lh[s.x >> 6], 1);
      atomicAdd(&lh[s.y >> 6], 1);
      atomicAdd(&lh[s.z >> 6], 1);
      atomicAdd(&lh[s.w >> 6], 1);
    }
  }
  __syncthreads();
  for (int j = tid; j < NB; j += 256) cnt2d[b * NB + j] = lh[j];
}

// ---------------------------------------------------------------------------
// K3 (3 launches): hierarchical exclusive scan over (bucket, rank) order,
// rank(b) = (b&7)*XG + (b>>3)  -> all blocks of one XCD are contiguous
// within each bucket, so each XCD's staged writes form ~1KB contiguous
// chunks per bucket (L2 absorbs partial lines; no cross-XCD thrash).
// ---------------------------------------------------------------------------
__device__ __forceinline__ int cnt2d_addr(int o) {
  const int j = o / NBLK2;
  const int rk = o - j * NBLK2;
  const int r = rk / XG;                // xcd
  const int q = rk - r * XG;            // index within xcd group
  return (q * 8 + r) * NB + j;
}

__global__ __launch_bounds__(256) void scan1_kernel(
    int* __restrict__ cnt2d, int* __restrict__ pt) {
  __shared__ int ws[4];
  const int tid = threadIdx.x, lane = tid & 63, wv = tid >> 6;
  const int o = blockIdx.x * 256 + tid;
  int addr = 0, v = 0;
  if (o < NE) { addr = cnt2d_addr(o); v = cnt2d[addr]; }
  int incl = v;
#pragma unroll
  for (int off = 1; off < 64; off <<= 1) {
    const int t = __shfl_up(incl, off);
    if (lane >= off) incl += t;
  }
  if (lane == 63) ws[wv] = incl;
  __syncthreads();
  int base = 0;
#pragma unroll
  for (int k = 0; k < 4; ++k)
    if (k < wv) base += ws[k];
  if (o < NE) cnt2d[addr] = base + incl - v;      // exclusive within block
  if (tid == 255) pt[blockIdx.x] = base + incl;   // block total
}

__global__ __launch_bounds__(256) void scan2_kernel(int* __restrict__ pt) {
  __shared__ int ts[256];
  const int t = threadIdx.x;
  int local[S2PER];
  int sum = 0;
#pragma unroll
  for (int k = 0; k < S2PER; ++k) {
    const int o = t * S2PER + k;
    const int v = (o < NS1) ? pt[o] : 0;
    local[k] = sum;
    sum += v;
  }
  ts[t] = sum;
  __syncthreads();
  for (int off = 1; off < 256; off <<= 1) {
    int tv = (t >= off) ? ts[t - off] : 0;
    __syncthreads();
    ts[t] += tv;
    __syncthreads();
  }
  const int ex = (t > 0) ? ts[t - 1] : 0;
#pragma unroll
  for (int k = 0; k < S2PER; ++k) {
    const int o = t * S2PER + k;
    if (o < NS1) pt[o] = ex + local[k];
  }
}

__global__ __launch_bounds__(256) void scan3_kernel(
    int* __restrict__ cnt2d, const int* __restrict__ pt,
    int* __restrict__ bstart) {
  const int o = blockIdx.x * 256 + threadIdx.x;
  if (o < NE) {
    const int addr = cnt2d_addr(o);
    const int excl = cnt2d[addr] + pt[blockIdx.x];
    cnt2d[addr] = excl;
    const int j = o / NBLK2;
    if (o - j * NBLK2 == 0) bstart[j] = excl;     // rank 0 -> bucket start
  }
  if (o == 0) bstart[NB] = N_EDGES;
}

// ---------------------------------------------------------------------------
// K4: deterministic-base scatter. Stage this block's scanned bases in LDS,
// bump with LDS atomics (rank within (block,bucket) arbitrary, same
// nondeterminism class as the proven pipeline). Zero global atomics.
// ---------------------------------------------------------------------------
__global__ __launch_bounds__(256) void scatter2_kernel(
    const int4* __restrict__ src4, const int4* __restrict__ dst4,
    const int* __restrict__ cnt2d, unsigned int* __restrict__ staged) {
  __shared__ int base[NB];
  const int tid = threadIdx.x, b = blockIdx.x;
  for (int j = tid; j < NB; j += 256) base[j] = cnt2d[b * NB + j];
  __syncthreads();
#pragma unroll
  for (int i = 0; i < 4; ++i) {
    const int idx4 = b * (EPB / 4) + i * 256 + tid;
    if (idx4 < N_EDGES / 4) {
      const int4 s = src4[idx4];
      const int4 d = dst4[idx4];
      int p;
      p = atomicAdd(&base[s.x >> 6], 1);
      staged[p] = ((unsigned)(s.x & 63) << 17) | (unsigned)d.x;
      p = atomicAdd(&base[s.y >> 6], 1);
      staged[p] = ((unsigned)(s.y & 63) << 17) | (unsigned)d.y;
      p = atomicAdd(&base[s.z >> 6], 1);
      staged[p] = ((unsigned)(s.z & 63) << 17) | (unsigned)d.z;
      p = atomicAdd(&base[s.w >> 6], 1);
      staged[p] = ((unsigned)(s.w & 63) << 17) | (unsigned)d.w;
    }
  }
}

// ---------------------------------------------------------------------------
// K5: one block per bucket. LDS counting sort by local src (ee computed
// once per edge), then register accumulate: wave owns 16 nodes, 4-edge
// batched bf16 gathers. Proven 152 us version, unchanged.
// ---------------------------------------------------------------------------
__global__ __launch_bounds__(256) void sort_aggregate_kernel(
    const int* __restrict__ bstart, const unsigned int* __restrict__ staged,
    const float* __restrict__ s_src, const float* __restrict__ s_dst,
    const __hip_bfloat16* __restrict__ h, float* __restrict__ out) {
  __shared__ uint2 eds[CAP];            // 24 KB
  __shared__ float ssrc[64];
  __shared__ int lcnt[64];
  __shared__ int lstart[65];
  __shared__ int lcur[64];

  const int b = blockIdx.x;
  const int tid = threadIdx.x;
  const int lane = tid & 63;
  const int wv = tid >> 6;
  const int node0 = b << 6;

  if (tid < 64)
    ssrc[tid] = (node0 + tid < N_NODES) ? s_src[node0 + tid] : 0.f;

  const int e0 = bstart[b];
  const int e1 = bstart[b + 1];

  float acc[16], rsn[16];
#pragma unroll
  for (int j = 0; j < 16; ++j) { acc[j] = 0.f; rsn[j] = 0.f; }

  for (int c0 = e0; c0 < e1; c0 += CAP) {
    const int cc = min(CAP, e1 - c0);
    __syncthreads();
    if (tid < 64) lcnt[tid] = 0;
    __syncthreads();

    // phase A: histogram of local src
    for (int i = tid; i < cc; i += 256)
      atomicAdd(&lcnt[staged[c0 + i] >> 17], 1);
    __syncthreads();

    // wave-0 scan of the 64 counters
    if (tid < 64) {
      int v = lcnt[tid];
#pragma unroll
      for (int off = 1; off < 64; off <<= 1) {
        int tv = __shfl_up(v, off);
        if (lane >= off) v += tv;
      }
      lstart[tid + 1] = v;
      if (tid == 0) lstart[0] = 0;
      lcur[tid] = v - lcnt[tid];
    }
    __syncthreads();

    // phase B: ee once per edge, scatter sorted into LDS (packed b64)
    for (int i = tid; i < cc; i += 256) {
      const unsigned pk = staged[c0 + i];
      const int ls = (int)(pk >> 17);
      const int d = (int)(pk & 0x1FFFFu);
      const float sc = ssrc[ls] + s_dst[d];
      const float lr = sc > 0.f ? sc : LRELU_SLOPE * sc;
      const float ev = __expf(-lr);
      const int p = atomicAdd(&lcur[ls], 1);
      eds[p] = make_uint2((unsigned)d, __float_as_uint(ev));
    }
    __syncthreads();

    // phase C: wave wv accumulates its 16 nodes in registers
#pragma unroll
    for (int j = 0; j < 16; ++j) {
      const int n = wv + 4 * j;
      const int iend = lstart[n + 1];
      int i = lstart[n];
      float p0 = 0.f, p1 = 0.f, rv = 0.f;
      for (; i + 4 <= iend; i += 4) {
        const uint2 q0 = eds[i + 0], q1 = eds[i + 1];
        const uint2 q2 = eds[i + 2], q3 = eds[i + 3];
        const float v0 = __uint_as_float(q0.y), v1 = __uint_as_float(q1.y);
        const float v2 = __uint_as_float(q2.y), v3 = __uint_as_float(q3.y);
        const float h0 = __bfloat162float(h[(size_t)q0.x * OUT_F + lane]);
        const float h1 = __bfloat162float(h[(size_t)q1.x * OUT_F + lane]);
        const float h2 = __bfloat162float(h[(size_t)q2.x * OUT_F + lane]);
        const float h3 = __bfloat162float(h[(size_t)q3.x * OUT_F + lane]);
        p0 += v0 * h0 + v2 * h2;
        p1 += v1 * h1 + v3 * h3;
        rv += (v0 + v1) + (v2 + v3);
      }
      for (; i < iend; ++i) {
        const uint2 q0 = eds[i];
        const float v0 = __uint_as_float(q0.y);
        p0 += v0 * __bfloat162float(h[(size_t)q0.x * OUT_F + lane]);
        rv += v0;
      }
      acc[j] += p0 + p1;
      rsn[j] += rv;
    }
  }

  // epilogue: out = elu(acc / rowsum)
#pragma unroll
  for (int j = 0; j < 16; ++j) {
    const int node = node0 + wv + 4 * j;
    if (node < N_NODES) {
      const float v = acc[j] / rsn[j];
      out[(size_t)node * OUT_F + lane] = v > 0.f ? v : expm1f(v);
    }
  }
}

extern "C" void kernel_launch(void* const* d_in, const int* in_sizes, int n_in,
                              void* d_out, int out_size, void* d_ws, size_t ws_size,
                              hipStream_t stream) {
  const float* in = (const float*)d_in[0];
  const int* edge = (const int*)d_in[1];
  const float* W = (const float*)d_in[2];
  const float* a = (const float*)d_in[3];
  float* out = (float*)d_out;

  const int4* src4 = (const int4*)edge;
  const int4* dst4 = (const int4*)(edge + N_EDGES);

  // workspace: identical to proven round-0 layout (26,639,100 B).
  // bctr region now unused (kept for layout stability).
  char* p = (char*)d_ws;
  __hip_bfloat16* h = (__hip_bfloat16*)p;  p += (size_t)N_NODES * OUT_F * 2;
  float* s_src = (float*)p;                p += (size_t)N_NODES * 4;
  float* s_dst = (float*)p;                p += (size_t)N_NODES * 4;
  unsigned int* staged = (unsigned int*)p; p += (size_t)N_EDGES * 4;
  int* bctr = (int*)p;                     p += (size_t)(NB * 32) * 4;
  int* bstart = (int*)p;                   p += (size_t)(NB + 1) * 4 + 12;
  __hip_bfloat16* wt = (__hip_bfloat16*)p; p += (size_t)OUT_F * IN_F * 2;
  (void)bctr;

  // scratch in d_out (fully overwritten by sort_aggregate afterwards):
  // cnt2d 784*1563*4 = 4.9 MB at offset 0, pt at offset 8 MB (19.2 KB).
  int* cnt2d = (int*)d_out;
  int* pt = (int*)((char*)d_out + (size_t)8 * 1024 * 1024);

  wt_kernel<<<OUT_F, 256, 0, stream>>>(W, wt);
  gemm_h_kernel<<<(N_NODES + 63) / 64, 256, 0, stream>>>(in, wt, a, h, s_src,
                                                         s_dst);
  hist2d_kernel<<<NBLK2, 256, 0, stream>>>(src4, cnt2d);
  scan1_kernel<<<NS1, 256, 0, stream>>>(cnt2d, pt);
  scan2_kernel<<<1, 256, 0, stream>>>(pt);
  scan3_kernel<<<NS1, 256, 0, stream>>>(cnt2d, pt, bstart);
  scatter2_kernel<<<NBLK2, 256, 0, stream>>>(src4, dst4, cnt2d, staged);
  sort_aggregate_kernel<<<NB, 256, 0, stream>>>(bstart, staged, s_src, s_dst,
                                                h, out);
}

// Round 8
// 382.917 us; speedup vs baseline: 4.5490x; 1.0877x over previous
//
#include <hip/hip_runtime.h>
#include <hip/hip_bf16.h>
#include <math.h>

#define N_NODES 100000
#define N_EDGES 3200000
#define IN_F 256
#define OUT_F 64
#define LRELU_SLOPE 0.2f

#define NB 1563                         // buckets of 64 src nodes
#define CAP 3072                        // K5 per-chunk LDS edge capacity

// deterministic partition geometry (scan-ordered cnt2d)
#define NBLK2 256                       // partition blocks (8 XCDs x 32)
#define XG 32                           // blocks per XCD group
#define I4PB (N_EDGES / 4 / NBLK2)      // 3125 int4 per partition block
#define NE (NB * NBLK2)                 // 400,128 scan elements
#define S2PER ((NB + 255) / 256)        // 7 elems/thread in scan2

typedef __attribute__((ext_vector_type(8))) short bf16x8;
typedef __attribute__((ext_vector_type(4))) float f32x4;

// ---------------------------------------------------------------------------
// K0: W (256x64 fp32) -> wt (64x256 bf16, transposed). 64 blocks x 256 thr.
// ---------------------------------------------------------------------------
__global__ __launch_bounds__(256) void wt_kernel(
    const float* __restrict__ W, __hip_bfloat16* __restrict__ wt) {
  wt[blockIdx.x * 256 + threadIdx.x] =
      __float2bfloat16(W[threadIdx.x * 64 + blockIdx.x]);
}

// ---------------------------------------------------------------------------
// K1: h = X @ W via bf16 MFMA 16x16x32, fused s_src = h@a[:64],
// s_dst = h@a[64:]. No LDS (proven ~13 us faster than LDS-staged).
// ---------------------------------------------------------------------------
__global__ __launch_bounds__(256) void gemm_h_kernel(
    const float* __restrict__ in, const __hip_bfloat16* __restrict__ wt,
    const float* __restrict__ a, __hip_bfloat16* __restrict__ h,
    float* __restrict__ s_src, float* __restrict__ s_dst) {
  const int tid = threadIdx.x;
  const int w = tid >> 6, lane = tid & 63;
  const int lm = lane & 15, lg = lane >> 4;
  const int arow = blockIdx.x * 64 + w * 16 + lm;   // this lane's A row
  const bool rv = arow < N_NODES;
  const float* xrow = &in[(size_t)(rv ? arow : 0) * IN_F + lg * 8];

  f32x4 acc[4];
#pragma unroll
  for (int ct = 0; ct < 4; ++ct) acc[ct] = (f32x4){0.f, 0.f, 0.f, 0.f};

  const __hip_bfloat16* wbase = &wt[(size_t)lm * IN_F + lg * 8];

#pragma unroll
  for (int kt = 0; kt < 8; ++kt) {
    float4 xa = make_float4(0.f, 0.f, 0.f, 0.f);
    float4 xb = make_float4(0.f, 0.f, 0.f, 0.f);
    if (rv) {
      xa = *(const float4*)(xrow + kt * 32);
      xb = *(const float4*)(xrow + kt * 32 + 4);
    }
    union { __hip_bfloat16 s[8]; bf16x8 v; } u;
    u.s[0] = __float2bfloat16(xa.x); u.s[1] = __float2bfloat16(xa.y);
    u.s[2] = __float2bfloat16(xa.z); u.s[3] = __float2bfloat16(xa.w);
    u.s[4] = __float2bfloat16(xb.x); u.s[5] = __float2bfloat16(xb.y);
    u.s[6] = __float2bfloat16(xb.z); u.s[7] = __float2bfloat16(xb.w);
    const bf16x8 af = u.v;
#pragma unroll
    for (int ct = 0; ct < 4; ++ct) {
      bf16x8 bfr = *(const bf16x8*)(wbase + (size_t)ct * 16 * IN_F + kt * 32);
      acc[ct] = __builtin_amdgcn_mfma_f32_16x16x32_bf16(af, bfr, acc[ct],
                                                        0, 0, 0);
    }
  }

  float as[4], ad[4];
#pragma unroll
  for (int ct = 0; ct < 4; ++ct) {
    as[ct] = a[ct * 16 + lm];
    ad[ct] = a[OUT_F + ct * 16 + lm];
  }
#pragma unroll
  for (int reg = 0; reg < 4; ++reg) {
    const int row = blockIdx.x * 64 + w * 16 + lg * 4 + reg;
    float vs = 0.f, vd = 0.f;
    if (row < N_NODES) {
#pragma unroll
      for (int ct = 0; ct < 4; ++ct) {
        const float v = acc[ct][reg];
        h[(size_t)row * OUT_F + ct * 16 + lm] = __float2bfloat16(v);
        vs += v * as[ct];
        vd += v * ad[ct];
      }
    }
#pragma unroll
    for (int m = 1; m < 16; m <<= 1) {    // reduce within quad group
      vs += __shfl_xor(vs, m);
      vd += __shfl_xor(vd, m);
    }
    if (lm == 0 && row < N_NODES) {
      s_src[row] = vs;
      s_dst[row] = vd;
    }
  }
}

// ---------------------------------------------------------------------------
// K2: per-block LDS histogram over all NB buckets, written TRANSPOSED into
// scan order: cnt2d[bucket*NBLK2 + rank(block)]. rank groups blocks by XCD
// (b&7), so the 16 consecutive ranks sharing a 64B cnt2d line are all
// written by one XCD -> L2 merges partial lines. 512 thr, zero glb atomics.
// ---------------------------------------------------------------------------
__global__ __launch_bounds__(512) void hist2d_kernel(
    const int4* __restrict__ src4, int* __restrict__ cnt2d) {
  __shared__ int lh[NB];
  const int tid = threadIdx.x, b = blockIdx.x;
  const int rank = (b & 7) * XG + (b >> 3);
  for (int j = tid; j < NB; j += 512) lh[j] = 0;
  __syncthreads();
  const int base4 = b * I4PB;
#pragma unroll
  for (int i = 0; i < 7; ++i) {
    const int k = i * 512 + tid;
    if (k < I4PB) {
      const int4 s = src4[base4 + k];
      atomicAdd(&lh[s.x >> 6], 1);
      atomicAdd(&lh[s.y >> 6], 1);
      atomicAdd(&lh[s.z >> 6], 1);
      atomicAdd(&lh[s.w >> 6], 1);
    }
  }
  __syncthreads();
  for (int j = tid; j < NB; j += 512) cnt2d[j * NBLK2 + rank] = lh[j];
}

// ---------------------------------------------------------------------------
// K3 (3 launches): hierarchical exclusive scan, now fully coalesced.
// scan1 block j == bucket j (256 contiguous rank entries); scan2 scans the
// 1563 bucket totals and emits bstart directly; scan3 adds bucket bases.
// ---------------------------------------------------------------------------
__global__ __launch_bounds__(256) void scan1_kernel(
    int* __restrict__ cnt2d, int* __restrict__ pt) {
  __shared__ int ws[4];
  const int tid = threadIdx.x, lane = tid & 63, wv = tid >> 6;
  const int o = blockIdx.x * 256 + tid;
  const int v = cnt2d[o];
  int incl = v;
#pragma unroll
  for (int off = 1; off < 64; off <<= 1) {
    const int t = __shfl_up(incl, off);
    if (lane >= off) incl += t;
  }
  if (lane == 63) ws[wv] = incl;
  __syncthreads();
  int base = 0;
#pragma unroll
  for (int k = 0; k < 4; ++k)
    if (k < wv) base += ws[k];
  cnt2d[o] = base + incl - v;                     // exclusive within bucket
  if (tid == 255) pt[blockIdx.x] = base + incl;   // bucket total
}

__global__ __launch_bounds__(256) void scan2_kernel(
    int* __restrict__ pt, int* __restrict__ bstart) {
  __shared__ int ts[256];
  const int t = threadIdx.x;
  int local[S2PER];
  int sum = 0;
#pragma unroll
  for (int k = 0; k < S2PER; ++k) {
    const int o = t * S2PER + k;
    const int v = (o < NB) ? pt[o] : 0;
    local[k] = sum;
    sum += v;
  }
  ts[t] = sum;
  __syncthreads();
  for (int off = 1; off < 256; off <<= 1) {
    int tv = (t >= off) ? ts[t - off] : 0;
    __syncthreads();
    ts[t] += tv;
    __syncthreads();
  }
  const int ex = (t > 0) ? ts[t - 1] : 0;
#pragma unroll
  for (int k = 0; k < S2PER; ++k) {
    const int o = t * S2PER + k;
    if (o < NB) {
      pt[o] = ex + local[k];
      bstart[o] = ex + local[k];
    }
  }
  if (t == 0) bstart[NB] = N_EDGES;
}

__global__ __launch_bounds__(256) void scan3_kernel(
    int* __restrict__ cnt2d, const int* __restrict__ pt) {
  const int o = blockIdx.x * 256 + threadIdx.x;
  cnt2d[o] += pt[blockIdx.x];          // block j == bucket j
}

// ---------------------------------------------------------------------------
// K4: deterministic-base scatter. Block b loads its scanned bases
// cnt2d[j*NBLK2 + rank(b)], bumps with LDS atomics, writes staged. Per
// (block,bucket) run ~8 edges; per XCD-group run ~1KB contiguous -> each
// XCD's staged working set ~1.6MB, L2-absorbed. Zero global atomics.
// ---------------------------------------------------------------------------
__global__ __launch_bounds__(512) void scatter2_kernel(
    const int4* __restrict__ src4, const int4* __restrict__ dst4,
    const int* __restrict__ cnt2d, unsigned int* __restrict__ staged) {
  __shared__ int base[NB];
  const int tid = threadIdx.x, b = blockIdx.x;
  const int rank = (b & 7) * XG + (b >> 3);
  for (int j = tid; j < NB; j += 512) base[j] = cnt2d[j * NBLK2 + rank];
  __syncthreads();
  const int base4 = b * I4PB;
#pragma unroll
  for (int i = 0; i < 7; ++i) {
    const int k = i * 512 + tid;
    if (k < I4PB) {
      const int4 s = src4[base4 + k];
      const int4 d = dst4[base4 + k];
      int p;
      p = atomicAdd(&base[s.x >> 6], 1);
      staged[p] = ((unsigned)(s.x & 63) << 17) | (unsigned)d.x;
      p = atomicAdd(&base[s.y >> 6], 1);
      staged[p] = ((unsigned)(s.y & 63) << 17) | (unsigned)d.y;
      p = atomicAdd(&base[s.z >> 6], 1);
      staged[p] = ((unsigned)(s.z & 63) << 17) | (unsigned)d.z;
      p = atomicAdd(&base[s.w >> 6], 1);
      staged[p] = ((unsigned)(s.w & 63) << 17) | (unsigned)d.w;
    }
  }
}

// ---------------------------------------------------------------------------
// K5: one block per bucket. LDS counting sort by local src (ee computed
// once per edge), then register accumulate: wave owns 16 nodes, 4-edge
// batched bf16 gathers. Proven 152 us version, unchanged.
// ---------------------------------------------------------------------------
__global__ __launch_bounds__(256) void sort_aggregate_kernel(
    const int* __restrict__ bstart, const unsigned int* __restrict__ staged,
    const float* __restrict__ s_src, const float* __restrict__ s_dst,
    const __hip_bfloat16* __restrict__ h, float* __restrict__ out) {
  __shared__ uint2 eds[CAP];            // 24 KB
  __shared__ float ssrc[64];
  __shared__ int lcnt[64];
  __shared__ int lstart[65];
  __shared__ int lcur[64];

  const int b = blockIdx.x;
  const int tid = threadIdx.x;
  const int lane = tid & 63;
  const int wv = tid >> 6;
  const int node0 = b << 6;

  if (tid < 64)
    ssrc[tid] = (node0 + tid < N_NODES) ? s_src[node0 + tid] : 0.f;

  const int e0 = bstart[b];
  const int e1 = bstart[b + 1];

  float acc[16], rsn[16];
#pragma unroll
  for (int j = 0; j < 16; ++j) { acc[j] = 0.f; rsn[j] = 0.f; }

  for (int c0 = e0; c0 < e1; c0 += CAP) {
    const int cc = min(CAP, e1 - c0);
    __syncthreads();
    if (tid < 64) lcnt[tid] = 0;
    __syncthreads();

    // phase A: histogram of local src
    for (int i = tid; i < cc; i += 256)
      atomicAdd(&lcnt[staged[c0 + i] >> 17], 1);
    __syncthreads();

    // wave-0 scan of the 64 counters
    if (tid < 64) {
      int v = lcnt[tid];
#pragma unroll
      for (int off = 1; off < 64; off <<= 1) {
        int tv = __shfl_up(v, off);
        if (lane >= off) v += tv;
      }
      lstart[tid + 1] = v;
      if (tid == 0) lstart[0] = 0;
      lcur[tid] = v - lcnt[tid];
    }
    __syncthreads();

    // phase B: ee once per edge, scatter sorted into LDS (packed b64)
    for (int i = tid; i < cc; i += 256) {
      const unsigned pk = staged[c0 + i];
      const int ls = (int)(pk >> 17);
      const int d = (int)(pk & 0x1FFFFu);
      const float sc = ssrc[ls] + s_dst[d];
      const float lr = sc > 0.f ? sc : LRELU_SLOPE * sc;
      const float ev = __expf(-lr);
      const int p = atomicAdd(&lcur[ls], 1);
      eds[p] = make_uint2((unsigned)d, __float_as_uint(ev));
    }
    __syncthreads();

    // phase C: wave wv accumulates its 16 nodes in registers
#pragma unroll
    for (int j = 0; j < 16; ++j) {
      const int n = wv + 4 * j;
      const int iend = lstart[n + 1];
      int i = lstart[n];
      float p0 = 0.f, p1 = 0.f, rv = 0.f;
      for (; i + 4 <= iend; i += 4) {
        const uint2 q0 = eds[i + 0], q1 = eds[i + 1];
        const uint2 q2 = eds[i + 2], q3 = eds[i + 3];
        const float v0 = __uint_as_float(q0.y), v1 = __uint_as_float(q1.y);
        const float v2 = __uint_as_float(q2.y), v3 = __uint_as_float(q3.y);
        const float h0 = __bfloat162float(h[(size_t)q0.x * OUT_F + lane]);
        const float h1 = __bfloat162float(h[(size_t)q1.x * OUT_F + lane]);
        const float h2 = __bfloat162float(h[(size_t)q2.x * OUT_F + lane]);
        const float h3 = __bfloat162float(h[(size_t)q3.x * OUT_F + lane]);
        p0 += v0 * h0 + v2 * h2;
        p1 += v1 * h1 + v3 * h3;
        rv += (v0 + v1) + (v2 + v3);
      }
      for (; i < iend; ++i) {
        const uint2 q0 = eds[i];
        const float v0 = __uint_as_float(q0.y);
        p0 += v0 * __bfloat162float(h[(size_t)q0.x * OUT_F + lane]);
        rv += v0;
      }
      acc[j] += p0 + p1;
      rsn[j] += rv;
    }
  }

  // epilogue: out = elu(acc / rowsum)
#pragma unroll
  for (int j = 0; j < 16; ++j) {
    const int node = node0 + wv + 4 * j;
    if (node < N_NODES) {
      const float v = acc[j] / rsn[j];
      out[(size_t)node * OUT_F + lane] = v > 0.f ? v : expm1f(v);
    }
  }
}

extern "C" void kernel_launch(void* const* d_in, const int* in_sizes, int n_in,
                              void* d_out, int out_size, void* d_ws, size_t ws_size,
                              hipStream_t stream) {
  const float* in = (const float*)d_in[0];
  const int* edge = (const int*)d_in[1];
  const float* W = (const float*)d_in[2];
  const float* a = (const float*)d_in[3];
  float* out = (float*)d_out;

  const int4* src4 = (const int4*)edge;
  const int4* dst4 = (const int4*)(edge + N_EDGES);

  // workspace: identical to proven round-0 layout (26,639,100 B).
  // bctr region unused (kept for layout stability).
  char* p = (char*)d_ws;
  __hip_bfloat16* h = (__hip_bfloat16*)p;  p += (size_t)N_NODES * OUT_F * 2;
  float* s_src = (float*)p;                p += (size_t)N_NODES * 4;
  float* s_dst = (float*)p;                p += (size_t)N_NODES * 4;
  unsigned int* staged = (unsigned int*)p; p += (size_t)N_EDGES * 4;
  int* bctr = (int*)p;                     p += (size_t)(NB * 32) * 4;
  int* bstart = (int*)p;                   p += (size_t)(NB + 1) * 4 + 12;
  __hip_bfloat16* wt = (__hip_bfloat16*)p; p += (size_t)OUT_F * IN_F * 2;
  (void)bctr;

  // scratch in d_out (fully overwritten by sort_aggregate afterwards):
  // cnt2d NB*NBLK2*4 = 1.6 MB at offset 0, pt at offset 8 MB (6.3 KB).
  int* cnt2d = (int*)d_out;
  int* pt = (int*)((char*)d_out + (size_t)8 * 1024 * 1024);

  wt_kernel<<<OUT_F, 256, 0, stream>>>(W, wt);
  gemm_h_kernel<<<(N_NODES + 63) / 64, 256, 0, stream>>>(in, wt, a, h, s_src,
                                                         s_dst);
  hist2d_kernel<<<NBLK2, 512, 0, stream>>>(src4, cnt2d);
  scan1_kernel<<<NB, 256, 0, stream>>>(cnt2d, pt);
  scan2_kernel<<<1, 256, 0, stream>>>(pt, bstart);
  scan3_kernel<<<NB, 256, 0, stream>>>(cnt2d, pt);
  scatter2_kernel<<<NBLK2, 512, 0, stream>>>(src4, dst4, cnt2d, staged);
  sort_aggregate_kernel<<<NB, 256, 0, stream>>>(bstart, staged, s_src, s_dst,
                                                h, out);
}